// Round 1
// 1036.942 us; speedup vs baseline: 1.0826x; 1.0826x over previous
//
#include <hip/hip_runtime.h>
#include <math.h>

// B=16, N=8192, L=512, D=384, FF=1536. INPUTS fp32, OUTPUT fp32.
// MFMA bf16 GEMMs, m97-style structure: 128x128 tile, linear LDS [128][32],
// global_load_lds width-16 async staging (no VGPR round-trip).
// Phase 1 processes G batches at once (G chosen from ws_size); phase 2 batched.

typedef unsigned short u16;
typedef unsigned int   u32;
typedef __bf16 bf16_t;
typedef bf16_t bf16x8 __attribute__((ext_vector_type(8)));
typedef float  floatx4 __attribute__((ext_vector_type(4)));

__device__ __forceinline__ float b2f(u16 v) {
    return __uint_as_float(((u32)v) << 16);
}
__device__ __forceinline__ u16 f2b(float f) {
    u32 u = __float_as_uint(f);
    return (u16)((u + 0x7FFFu + ((u >> 16) & 1u)) >> 16);   // RNE
}
__device__ __forceinline__ void stb4(u16* p, float4 f) {
    uint2 v;
    v.x = (u32)f2b(f.x) | ((u32)f2b(f.y) << 16);
    v.y = (u32)f2b(f.z) | ((u32)f2b(f.w) << 16);
    *(uint2*)p = v;
}

// async global->LDS, 16B per lane; LDS dest is wave-uniform base + lane*16.
__device__ __forceinline__ void gl2lds16(u16* lds, const u16* g) {
    __builtin_amdgcn_global_load_lds(
        (const __attribute__((address_space(1))) void*)g,
        (__attribute__((address_space(3))) void*)lds, 16, 0, 0);
}

// ---------------------------------------------------------------------------
// Weight convert: W fp32 [Kd][Nd] -> WT bf16 [Nd][Kd]
__global__ __launch_bounds__(256) void wconv_kernel(
    const float* __restrict__ W, u16* __restrict__ WT, int Kd, int Nd)
{
    int idx = blockIdx.x * 256 + threadIdx.x;
    if (idx >= Kd * Nd) return;
    int n = idx / Kd, k = idx - n * Kd;
    WT[idx] = f2b(W[(long long)k * Nd + n]);
}

// ---------------------------------------------------------------------------
// Layer 0: h = relu(x @ w0 + b0); x fp32 [M][3], out bf16
__global__ __launch_bounds__(256) void layer0_kernel(
    const float* __restrict__ X, const float* __restrict__ W0,
    const float* __restrict__ B0, u16* __restrict__ H, int total4)
{
    int idx = blockIdx.x * 256 + threadIdx.x;
    if (idx >= total4) return;
    int e = idx * 4;
    int m = e / 384;
    int j = e - m * 384;
    float x0 = X[m * 3 + 0], x1 = X[m * 3 + 1], x2 = X[m * 3 + 2];
    float4 w0 = *(const float4*)(W0 + j);
    float4 w1 = *(const float4*)(W0 + 384 + j);
    float4 w2 = *(const float4*)(W0 + 768 + j);
    float4 bb = *(const float4*)(B0 + j);
    float4 v;
    v.x = fmaxf(bb.x + x0 * w0.x + x1 * w1.x + x2 * w2.x, 0.f);
    v.y = fmaxf(bb.y + x0 * w0.y + x1 * w1.y + x2 * w2.y, 0.f);
    v.z = fmaxf(bb.z + x0 * w0.z + x1 * w1.z + x2 * w2.z, 0.f);
    v.w = fmaxf(bb.w + x0 * w0.w + x1 * w1.w + x2 * w2.w, 0.f);
    stb4(H + e, v);
}

// ---------------------------------------------------------------------------
// LayerNorm; input fp32 (IN_F32=1) or bf16; g,b fp32; out bf16. 4 rows/block.
template<int IN_F32>
__global__ __launch_bounds__(256) void ln_kernel(
    const void* __restrict__ Xv, const float* __restrict__ g,
    const float* __restrict__ b, u16* __restrict__ Y, int rows)
{
    int w = threadIdx.x >> 6, lane = threadIdx.x & 63;
    int row = blockIdx.x * 4 + w;
    if (row >= rows) return;
    float v[6];
    float s = 0.f, ss = 0.f;
#pragma unroll
    for (int i = 0; i < 6; ++i) {
        int c = i * 64 + lane;
        v[i] = IN_F32 ? ((const float*)Xv)[(long long)row * 384 + c]
                      : b2f(((const u16*)Xv)[(long long)row * 384 + c]);
        s += v[i]; ss += v[i] * v[i];
    }
#pragma unroll
    for (int m = 32; m; m >>= 1) {
        s  += __shfl_xor(s, m, 64);
        ss += __shfl_xor(ss, m, 64);
    }
    float mean = s * (1.0f / 384.0f);
    float var  = ss * (1.0f / 384.0f) - mean * mean;
    float rs = rsqrtf(fmaxf(var, 0.f) + 1e-5f);
    u16* yr = Y + (long long)row * 384;
#pragma unroll
    for (int i = 0; i < 6; ++i) {
        int c = i * 64 + lane;
        yr[c] = f2b((v[i] - mean) * rs * g[c] + b[c]);
    }
}

// ---------------------------------------------------------------------------
// m97-style 128x128 tile K-loop: linear LDS [128][32], global_load_lds w16.
// Per k-step: 4 async issues per wave, 2 barriers, 16 MFMA per wave.
#define MFMA_TILE_LOOP128(Aptr, Bptr, LDA, LDB, K0, K1)                        \
    for (int k0 = (K0); k0 < (K1); k0 += 32) {                                 \
        __syncthreads();                                                       \
        {                                                                      \
            int rlo = lane >> 2;                                               \
            int c8 = (lane & 3) * 8;                                           \
            gl2lds16(&As[(wv * 32) * 32],                                      \
                (Aptr) + (long long)(m0 + wv * 32 + rlo) * (LDA) + k0 + c8);   \
            gl2lds16(&As[(wv * 32 + 16) * 32],                                 \
                (Aptr) + (long long)(m0 + wv * 32 + 16 + rlo) * (LDA) + k0 + c8); \
            gl2lds16(&Bs[(wv * 32) * 32],                                      \
                (Bptr) + (long long)(n0 + wv * 32 + rlo) * (LDB) + k0 + c8);   \
            gl2lds16(&Bs[(wv * 32 + 16) * 32],                                 \
                (Bptr) + (long long)(n0 + wv * 32 + 16 + rlo) * (LDB) + k0 + c8); \
        }                                                                      \
        __syncthreads();                                                       \
        bf16x8 a0 = *(const bf16x8*)&As[(wv * 32 + lr) * 32 + lq * 8];         \
        bf16x8 a1 = *(const bf16x8*)&As[(wv * 32 + 16 + lr) * 32 + lq * 8];    \
        _Pragma("unroll")                                                      \
        for (int ns = 0; ns < 8; ++ns) {                                       \
            bf16x8 b = *(const bf16x8*)&Bs[(ns * 16 + lr) * 32 + lq * 8];      \
            acc[0][ns] = __builtin_amdgcn_mfma_f32_16x16x32_bf16(a0, b, acc[0][ns], 0, 0, 0); \
            acc[1][ns] = __builtin_amdgcn_mfma_f32_16x16x32_bf16(a1, b, acc[1][ns], 0, 0, 0); \
        }                                                                      \
    }

// Generic GEMM with z-strides: C = act(scale*A@WT^T + bias) + res.
template<int RES_F32, int OUT_F32>
__global__ __launch_bounds__(256) void gemm_mfma(
    const u16* __restrict__ A, const u16* __restrict__ WT,
    const float* __restrict__ bias, const void* __restrict__ res,
    void* __restrict__ C,
    int M, int N, int K, int lda, int ldb, int ldc, int ldres,
    float scale, int relu, int resmask,
    long long zsA, long long zsB, long long zsC)
{
    __shared__ u16 As[128 * 32];
    __shared__ u16 Bs[128 * 32];
    const int tid = threadIdx.x;
    const int wv = tid >> 6, lane = tid & 63;
    const int lr = lane & 15, lq = lane >> 4;
    const int m0 = blockIdx.x * 128;
    const int n0 = blockIdx.y * 128;
    const u16* Az = A + blockIdx.z * zsA;
    const u16* Bz = WT + blockIdx.z * zsB;
    const long long czoff = blockIdx.z * zsC;

    floatx4 acc[2][8];
#pragma unroll
    for (int i = 0; i < 2; ++i)
#pragma unroll
        for (int j = 0; j < 8; ++j)
            acc[i][j] = (floatx4){0.f, 0.f, 0.f, 0.f};

    MFMA_TILE_LOOP128(Az, Bz, lda, ldb, 0, K)

#pragma unroll
    for (int ms = 0; ms < 2; ++ms) {
#pragma unroll
        for (int ns = 0; ns < 8; ++ns) {
            int col = n0 + ns * 16 + lr;
            float bi = bias ? bias[col] : 0.f;
#pragma unroll
            for (int r = 0; r < 4; ++r) {
                int m = m0 + wv * 32 + ms * 16 + lq * 4 + r;
                float v = acc[ms][ns][r] * scale + bi;
                if (relu) v = fmaxf(v, 0.f);
                if (res) {
                    long long ro = (long long)(m & resmask) * ldres + col;
                    v += RES_F32 ? ((const float*)res)[ro]
                                 : b2f(((const u16*)res)[ro]);
                }
                long long co = czoff + (long long)m * ldc + col;
                if (OUT_F32) ((float*)C)[co] = v;
                else         ((u16*)C)[co] = f2b(v);
            }
        }
    }
}

// ---------------------------------------------------------------------------
// S-with-exp GEMM (z over group): P = exp(clamp(scale*q@K^T)), den += row sums.
__global__ __launch_bounds__(256) void gemm_exp(
    const u16* __restrict__ A, const u16* __restrict__ WT,
    u16* __restrict__ P, float* __restrict__ den,
    int K, int lda, int ldb, int ldc, float scale,
    long long zsB, long long zsP)
{
    __shared__ u16 As[128 * 32];
    __shared__ u16 Bs[128 * 32];
    const int tid = threadIdx.x;
    const int wv = tid >> 6, lane = tid & 63;
    const int lr = lane & 15, lq = lane >> 4;
    const int m0 = blockIdx.x * 128;
    const int n0 = blockIdx.y * 128;
    const u16* Bz = WT + blockIdx.z * zsB;
    u16* Pz = P + blockIdx.z * zsP;
    float* dz = den + blockIdx.z * 512;

    floatx4 acc[2][8];
#pragma unroll
    for (int i = 0; i < 2; ++i)
#pragma unroll
        for (int j = 0; j < 8; ++j)
            acc[i][j] = (floatx4){0.f, 0.f, 0.f, 0.f};

    MFMA_TILE_LOOP128(A, Bz, lda, ldb, 0, K)

    float srow[2][4] = {};
#pragma unroll
    for (int ms = 0; ms < 2; ++ms) {
#pragma unroll
        for (int ns = 0; ns < 8; ++ns) {
            int col = n0 + ns * 16 + lr;
#pragma unroll
            for (int r = 0; r < 4; ++r) {
                int m = m0 + wv * 32 + ms * 16 + lq * 4 + r;
                float l = acc[ms][ns][r] * scale;
                l = fminf(fmaxf(l, -60.f), 60.f);
                float p = __expf(l);
                Pz[(long long)m * ldc + col] = f2b(p);
                srow[ms][r] += p;
            }
        }
    }
#pragma unroll
    for (int ms = 0; ms < 2; ++ms)
#pragma unroll
        for (int r = 0; r < 4; ++r) {
            float s = srow[ms][r];
            s += __shfl_xor(s, 1, 64);
            s += __shfl_xor(s, 2, 64);
            s += __shfl_xor(s, 4, 64);
            s += __shfl_xor(s, 8, 64);
            if (lr == 0)
                atomicAdd(&dz[m0 + wv * 32 + ms * 16 + lq * 4 + r], s);
        }
}

// ---------------------------------------------------------------------------
// Split-K PV over group: z = g*SPLIT + s; part[z] = P_g[:, ks..] @ VT_g[:, ks..]^T
__global__ __launch_bounds__(256) void gemm_pv(
    const u16* __restrict__ P, const u16* __restrict__ VT,
    float* __restrict__ part, int SPLIT)
{
    __shared__ u16 As[128 * 32];
    __shared__ u16 Bs[128 * 32];
    const int tid = threadIdx.x;
    const int wv = tid >> 6, lane = tid & 63;
    const int lr = lane & 15, lq = lane >> 4;
    const int m0 = blockIdx.x * 128;
    const int n0 = blockIdx.y * 128;
    const int z = blockIdx.z;
    const int g = z / SPLIT, sp = z - g * SPLIT;
    const int chunk = 8192 / SPLIT;
    const u16* Az = P + (long long)g * 512 * 8192;
    const u16* Bz = VT + (long long)g * 384 * 8192;

    floatx4 acc[2][8];
#pragma unroll
    for (int i = 0; i < 2; ++i)
#pragma unroll
        for (int j = 0; j < 8; ++j)
            acc[i][j] = (floatx4){0.f, 0.f, 0.f, 0.f};

    MFMA_TILE_LOOP128(Az, Bz, 8192, 8192, sp * chunk, (sp + 1) * chunk)

    float* pz = part + (long long)z * 512 * 384;
#pragma unroll
    for (int ms = 0; ms < 2; ++ms)
#pragma unroll
        for (int ns = 0; ns < 8; ++ns) {
            int col = n0 + ns * 16 + lr;
#pragma unroll
            for (int r = 0; r < 4; ++r) {
                int m = m0 + wv * 32 + ms * 16 + lq * 4 + r;
                pz[(long long)m * 384 + col] = acc[ms][ns][r];
            }
        }
}

// ---------------------------------------------------------------------------
// PV reduce over group: ao[g][q][d] = (sum_s part[g*SPLIT+s][q][d]) / den[g*512+q]
__global__ __launch_bounds__(256) void pv_reduce_kernel(
    const float* __restrict__ part, const float* __restrict__ den,
    u16* __restrict__ AO, int SPLIT)
{
    int idx = blockIdx.x * 256 + threadIdx.x;   // G*512*96 threads
    int q = idx / 96, j = (idx - q * 96) * 4;   // q in [0, G*512)
    int g = q >> 9, ql = q & 511;
    float4 s = make_float4(0.f, 0.f, 0.f, 0.f);
    for (int sp = 0; sp < SPLIT; ++sp) {
        const float* pz = part + (((long long)(g * SPLIT + sp) * 512 + ql) * 384 + j);
        float4 v = *(const float4*)pz;
        s.x += v.x; s.y += v.y; s.z += v.z; s.w += v.w;
    }
    float inv = 1.0f / den[q];
    s.x *= inv; s.y *= inv; s.z *= inv; s.w *= inv;
    stb4(AO + (long long)q * 384 + j, s);
}

// ---------------------------------------------------------------------------
// FF1 + GEGLU fused: gl = a * gelu(g). 128x(64+64) tile, async staging.
__global__ __launch_bounds__(256) void gemm_ff1_geglu(
    const u16* __restrict__ A, const u16* __restrict__ WT,
    const float* __restrict__ bias, u16* __restrict__ C,
    int K, int lda, int ldb, int ldc)
{
    __shared__ u16 As[128 * 32];
    __shared__ u16 Bs[128 * 32];
    const int tid = threadIdx.x;
    const int wv = tid >> 6, lane = tid & 63;
    const int lr = lane & 15, lq = lane >> 4;
    const int m0 = blockIdx.x * 128;
    const int n0 = blockIdx.y * 64;

    floatx4 accA[2][4], accG[2][4];
#pragma unroll
    for (int i = 0; i < 2; ++i)
#pragma unroll
        for (int j = 0; j < 4; ++j) {
            accA[i][j] = (floatx4){0.f, 0.f, 0.f, 0.f};
            accG[i][j] = (floatx4){0.f, 0.f, 0.f, 0.f};
        }

    for (int k0 = 0; k0 < K; k0 += 32) {
        __syncthreads();
        {
            int rlo = lane >> 2;
            int c8 = (lane & 3) * 8;
            gl2lds16(&As[(wv * 32) * 32],
                A + (long long)(m0 + wv * 32 + rlo) * lda + k0 + c8);
            gl2lds16(&As[(wv * 32 + 16) * 32],
                A + (long long)(m0 + wv * 32 + 16 + rlo) * lda + k0 + c8);
            int r0 = wv * 32 + rlo;
            int r1 = r0 + 16;
            int wrow0 = (r0 < 64) ? (n0 + r0) : (1536 + n0 + r0 - 64);
            int wrow1 = (r1 < 64) ? (n0 + r1) : (1536 + n0 + r1 - 64);
            gl2lds16(&Bs[(wv * 32) * 32],
                WT + (long long)wrow0 * ldb + k0 + c8);
            gl2lds16(&Bs[(wv * 32 + 16) * 32],
                WT + (long long)wrow1 * ldb + k0 + c8);
        }
        __syncthreads();
        bf16x8 a0 = *(const bf16x8*)&As[(wv * 32 + lr) * 32 + lq * 8];
        bf16x8 a1 = *(const bf16x8*)&As[(wv * 32 + 16 + lr) * 32 + lq * 8];
#pragma unroll
        for (int ns = 0; ns < 4; ++ns) {
            bf16x8 bA = *(const bf16x8*)&Bs[(ns * 16 + lr) * 32 + lq * 8];
            bf16x8 bG = *(const bf16x8*)&Bs[((64 + ns * 16) + lr) * 32 + lq * 8];
            accA[0][ns] = __builtin_amdgcn_mfma_f32_16x16x32_bf16(a0, bA, accA[0][ns], 0, 0, 0);
            accA[1][ns] = __builtin_amdgcn_mfma_f32_16x16x32_bf16(a1, bA, accA[1][ns], 0, 0, 0);
            accG[0][ns] = __builtin_amdgcn_mfma_f32_16x16x32_bf16(a0, bG, accG[0][ns], 0, 0, 0);
            accG[1][ns] = __builtin_amdgcn_mfma_f32_16x16x32_bf16(a1, bG, accG[1][ns], 0, 0, 0);
        }
    }

#pragma unroll
    for (int ms = 0; ms < 2; ++ms)
#pragma unroll
        for (int ns = 0; ns < 4; ++ns) {
            int col = n0 + ns * 16 + lr;
            float ba = bias[col];
            float bg = bias[1536 + col];
#pragma unroll
            for (int r = 0; r < 4; ++r) {
                int m = m0 + wv * 32 + ms * 16 + lq * 4 + r;
                float a = accA[ms][ns][r] + ba;
                float g = accG[ms][ns][r] + bg;
                float v = a * 0.5f * g * (1.0f + erff(g * 0.70710678118654752f));
                C[(long long)m * ldc + col] = f2b(v);
            }
        }
}

// ---------------------------------------------------------------------------
extern "C" void kernel_launch(void* const* d_in, const int* in_sizes, int n_in,
                              void* d_out, int out_size, void* d_ws, size_t ws_size,
                              hipStream_t stream) {
    const float* x     = (const float*)d_in[0];
    const float* w0    = (const float*)d_in[1];
    const float* b0    = (const float*)d_in[2];
    const float* w1    = (const float*)d_in[3];
    const float* b1    = (const float*)d_in[4];
    const float* w2    = (const float*)d_in[5];
    const float* b2    = (const float*)d_in[6];
    const float* w3    = (const float*)d_in[7];
    const float* b3    = (const float*)d_in[8];
    const float* query = (const float*)d_in[9];
    const float* lnqg  = (const float*)d_in[10];
    const float* lnqb  = (const float*)d_in[11];
    const float* lncg  = (const float*)d_in[12];
    const float* lncb  = (const float*)d_in[13];
    const float* wq    = (const float*)d_in[14];
    const float* wkv   = (const float*)d_in[15];
    const float* wo    = (const float*)d_in[16];
    const float* bo    = (const float*)d_in[17];
    const float* lnfg  = (const float*)d_in[18];
    const float* lnfb  = (const float*)d_in[19];
    const float* ffw1  = (const float*)d_in[20];
    const float* ffb1  = (const float*)d_in[21];
    const float* ffw2  = (const float*)d_in[22];
    const float* ffb2  = (const float*)d_in[23];
    float* out = (float*)d_out;
    char* wsb = (char*)d_ws;

    // ---- group size selection from ws_size ----
    auto need = [](int G) -> size_t {
        return (size_t)G * (3LL * 6291456 + 8388608)    // bufA,bufB,VT,P
             + 25165824                                 // part (32 slots)
             + 6291456                                  // ao_all
             + 2 * 393216 + 32768                       // qn, qb, den
             + 5603328;                                 // weight pool
    };
    int G = 2;
    if      (ws_size >= need(16)) G = 16;
    else if (ws_size >= need(8))  G = 8;
    else if (ws_size >= need(4))  G = 4;
    const int SPLIT = 32 / G;

    long long off = 0;
    u16*   bufA   = (u16*)(wsb + off); off += (long long)G * 6291456;
    u16*   bufB   = (u16*)(wsb + off); off += (long long)G * 6291456;
    u16*   VTb    = (u16*)(wsb + off); off += (long long)G * 6291456;
    u16*   Pb     = (u16*)(wsb + off); off += (long long)G * 8388608;
    float* part   = (float*)(wsb + off); off += 25165824;
    u16*   ao_all = (u16*)(wsb + off); off += 6291456;
    u16*   qn     = (u16*)(wsb + off); off += 393216;
    u16*   qb     = (u16*)(wsb + off); off += 393216;
    float* den    = (float*)(wsb + off); off += 32768;
    u16*   w1T    = (u16*)(wsb + off); off += 294912;
    u16*   w2T    = (u16*)(wsb + off); off += 294912;
    u16*   w3T    = (u16*)(wsb + off); off += 294912;
    u16*   wqT    = (u16*)(wsb + off); off += 294912;
    u16*   wkvT   = (u16*)(wsb + off); off += 589824;   // +147456 elems = wvT
    u16*   woT    = (u16*)(wsb + off); off += 294912;
    u16*   ffw1T  = (u16*)(wsb + off); off += 2359296;
    u16*   ffw2T  = (u16*)(wsb + off); off += 1179648;
    // phase-2 overlays (bufA/bufB/VT region is dead by then; >= 37.75MB for G>=2)
    u16*   x1_all = (u16*)(wsb + 0);
    u16*   f0_all = (u16*)(wsb + 6291456);
    u16*   gl_all = (u16*)(wsb + 12582912);   // 25.2MB, ends at 37748736

    const int FULLMASK = 0x3FFFFFFF;

    // ---- setup ----
    wconv_kernel<<<576,  256, 0, stream>>>(w1,   w1T,   384, 384);
    wconv_kernel<<<576,  256, 0, stream>>>(w2,   w2T,   384, 384);
    wconv_kernel<<<576,  256, 0, stream>>>(w3,   w3T,   384, 384);
    wconv_kernel<<<576,  256, 0, stream>>>(wq,   wqT,   384, 384);
    wconv_kernel<<<1152, 256, 0, stream>>>(wkv,  wkvT,  384, 768);
    wconv_kernel<<<576,  256, 0, stream>>>(wo,   woT,   384, 384);
    wconv_kernel<<<4608, 256, 0, stream>>>(ffw1, ffw1T, 384, 3072);
    wconv_kernel<<<2304, 256, 0, stream>>>(ffw2, ffw2T, 1536, 384);
    hipMemsetAsync(den, 0, 16 * 512 * sizeof(float), stream);
    ln_kernel<1><<<128, 256, 0, stream>>>(query, lnqg, lnqb, qn, 512);
    gemm_mfma<0, 0><<<dim3(4, 3), 256, 0, stream>>>(qn, wqT, nullptr, nullptr, qb,
        512, 384, 384, 384, 384, 384, 0, 1.f, 0, FULLMASK, 0, 0, 0);

    // ---- phase 1: groups of G batches ----
    const int MG = G * 8192;
    for (int base = 0; base < 16; base += G) {
        const float* xg = x + (long long)base * 24576;

        layer0_kernel<<<G * 3072, 256, 0, stream>>>(xg, w0, b0, bufA, G * 786432);
        gemm_mfma<0, 0><<<dim3(MG / 128, 3), 256, 0, stream>>>(bufA, w1T, b1, nullptr, bufB,
            MG, 384, 384, 384, 384, 384, 0, 1.f, 1, FULLMASK, 0, 0, 0);
        gemm_mfma<0, 0><<<dim3(MG / 128, 3), 256, 0, stream>>>(bufB, w2T, b2, nullptr, bufA,
            MG, 384, 384, 384, 384, 384, 0, 1.f, 1, FULLMASK, 0, 0, 0);
        gemm_mfma<0, 0><<<dim3(MG / 128, 3), 256, 0, stream>>>(bufA, w3T, b3, nullptr, bufB,
            MG, 384, 384, 384, 384, 384, 0, 1.f, 0, FULLMASK, 0, 0, 0);   // ctx -> bufB
        ln_kernel<0><<<MG / 4, 256, 0, stream>>>(bufB, lncg, lncb, bufA, MG);  // kn -> bufA
        // K_all = kn @ wk -> bufB
        gemm_mfma<0, 0><<<dim3(MG / 128, 3), 256, 0, stream>>>(bufA, wkvT, nullptr, nullptr, bufB,
            MG, 384, 384, 384, 384, 384, 0, 1.f, 0, FULLMASK, 0, 0, 0);
        // VT_g = wv^T @ kn_g^T  (z over group)
        gemm_mfma<0, 0><<<dim3(3, 64, G), 256, 0, stream>>>(wkvT + 147456, bufA,
            nullptr, nullptr, VTb, 384, 8192, 384, 384, 384, 8192, 0, 1.f, 0, FULLMASK,
            0, 8192LL * 384, 384LL * 8192);
        // P_g = exp(scale * q @ K_g^T), den += row sums
        gemm_exp<<<dim3(4, 64, G), 256, 0, stream>>>(qb, bufB, Pb, den + base * 512,
            384, 384, 384, 8192, 0.05103103630798288f, 8192LL * 384, 512LL * 8192);
        // PV split-K partials (z = g*SPLIT + s, 32 total)
        gemm_pv<<<dim3(4, 3, 32), 256, 0, stream>>>(Pb, VTb, part, SPLIT);
        // reduce -> ao_all[base..base+G)
        pv_reduce_kernel<<<G * 192, 256, 0, stream>>>(part, den + base * 512,
            ao_all + (long long)base * 196608, SPLIT);
    }

    // ---- phase 2: batched across all 16 ----
    gemm_mfma<1, 0><<<dim3(64, 3), 256, 0, stream>>>(ao_all, woT, bo, query, x1_all,
        8192, 384, 384, 384, 384, 384, 384, 1.f, 0, 511, 0, 0, 0);
    ln_kernel<0><<<2048, 256, 0, stream>>>(x1_all, lnfg, lnfb, f0_all, 8192);
    gemm_ff1_geglu<<<dim3(64, 24), 256, 0, stream>>>(f0_all, ffw1T, ffb1, gl_all,
        384, 384, 384, 1536);
    gemm_mfma<0, 1><<<dim3(64, 3), 256, 0, stream>>>(gl_all, ffw2T, ffb2, x1_all, out,
        8192, 384, 1536, 1536, 1536, 384, 384, 1.f, 0, FULLMASK, 0, 0, 0);
}

// Round 2
// 986.228 us; speedup vs baseline: 1.1382x; 1.0514x over previous
//
#include <hip/hip_runtime.h>
#include <math.h>

// B=16, N=8192, L=512, D=384, FF=1536. INPUTS fp32, OUTPUT fp32.
// MFMA bf16 GEMMs, m97-style structure: 128x128 tile, linear LDS [128][32],
// global_load_lds width-16 async staging. XCD-chunked block remap for L2
// locality; gemm_exp streams P via LDS transpose (full-line 16B stores).

typedef unsigned short u16;
typedef unsigned int   u32;
typedef __bf16 bf16_t;
typedef bf16_t bf16x8 __attribute__((ext_vector_type(8)));
typedef float  floatx4 __attribute__((ext_vector_type(4)));

__device__ __forceinline__ float b2f(u16 v) {
    return __uint_as_float(((u32)v) << 16);
}
__device__ __forceinline__ u16 f2b(float f) {
    u32 u = __float_as_uint(f);
    return (u16)((u + 0x7FFFu + ((u >> 16) & 1u)) >> 16);   // RNE
}
__device__ __forceinline__ void stb4(u16* p, float4 f) {
    uint2 v;
    v.x = (u32)f2b(f.x) | ((u32)f2b(f.y) << 16);
    v.y = (u32)f2b(f.z) | ((u32)f2b(f.w) << 16);
    *(uint2*)p = v;
}

// async global->LDS, 16B per lane; LDS dest is wave-uniform base + lane*16.
__device__ __forceinline__ void gl2lds16(u16* lds, const u16* g) {
    __builtin_amdgcn_global_load_lds(
        (const __attribute__((address_space(1))) void*)g,
        (__attribute__((address_space(3))) void*)lds, 16, 0, 0);
}

// Bijective XCD-chunked remap: physical block p lands on XCD p%8; give each
// XCD a contiguous chunk of the logical grid so blocks sharing a B-panel
// share one XCD's L2. Identity when nb % 8 != 0 (ERRATA #11 bijectivity).
__device__ __forceinline__ void xcd_remap(int& bx, int& by, int& bz) {
    int gx = gridDim.x, gy = gridDim.y, gz = gridDim.z;
    int nb = gx * gy * gz;
    int p = bx + gx * (by + gy * bz);
    if ((nb & 7) == 0) {
        int chunk = nb >> 3;
        p = (p & 7) * chunk + (p >> 3);
    }
    bx = p % gx;
    int t = p / gx;
    by = t % gy;
    bz = t / gy;
}

// ---------------------------------------------------------------------------
// Weight convert: W fp32 [Kd][Nd] -> WT bf16 [Nd][Kd]
__global__ __launch_bounds__(256) void wconv_kernel(
    const float* __restrict__ W, u16* __restrict__ WT, int Kd, int Nd)
{
    int idx = blockIdx.x * 256 + threadIdx.x;
    if (idx >= Kd * Nd) return;
    int n = idx / Kd, k = idx - n * Kd;
    WT[idx] = f2b(W[(long long)k * Nd + n]);
}

// ---------------------------------------------------------------------------
// Layer 0: h = relu(x @ w0 + b0); x fp32 [M][3], out bf16
__global__ __launch_bounds__(256) void layer0_kernel(
    const float* __restrict__ X, const float* __restrict__ W0,
    const float* __restrict__ B0, u16* __restrict__ H, int total4)
{
    int idx = blockIdx.x * 256 + threadIdx.x;
    if (idx >= total4) return;
    int e = idx * 4;
    int m = e / 384;
    int j = e - m * 384;
    float x0 = X[m * 3 + 0], x1 = X[m * 3 + 1], x2 = X[m * 3 + 2];
    float4 w0 = *(const float4*)(W0 + j);
    float4 w1 = *(const float4*)(W0 + 384 + j);
    float4 w2 = *(const float4*)(W0 + 768 + j);
    float4 bb = *(const float4*)(B0 + j);
    float4 v;
    v.x = fmaxf(bb.x + x0 * w0.x + x1 * w1.x + x2 * w2.x, 0.f);
    v.y = fmaxf(bb.y + x0 * w0.y + x1 * w1.y + x2 * w2.y, 0.f);
    v.z = fmaxf(bb.z + x0 * w0.z + x1 * w1.z + x2 * w2.z, 0.f);
    v.w = fmaxf(bb.w + x0 * w0.w + x1 * w1.w + x2 * w2.w, 0.f);
    stb4(H + e, v);
}

// ---------------------------------------------------------------------------
// LayerNorm; input fp32 (IN_F32=1) or bf16; g,b fp32; out bf16. 4 rows/block.
template<int IN_F32>
__global__ __launch_bounds__(256) void ln_kernel(
    const void* __restrict__ Xv, const float* __restrict__ g,
    const float* __restrict__ b, u16* __restrict__ Y, int rows)
{
    int w = threadIdx.x >> 6, lane = threadIdx.x & 63;
    int row = blockIdx.x * 4 + w;
    if (row >= rows) return;
    float v[6];
    float s = 0.f, ss = 0.f;
#pragma unroll
    for (int i = 0; i < 6; ++i) {
        int c = i * 64 + lane;
        v[i] = IN_F32 ? ((const float*)Xv)[(long long)row * 384 + c]
                      : b2f(((const u16*)Xv)[(long long)row * 384 + c]);
        s += v[i]; ss += v[i] * v[i];
    }
#pragma unroll
    for (int m = 32; m; m >>= 1) {
        s  += __shfl_xor(s, m, 64);
        ss += __shfl_xor(ss, m, 64);
    }
    float mean = s * (1.0f / 384.0f);
    float var  = ss * (1.0f / 384.0f) - mean * mean;
    float rs = rsqrtf(fmaxf(var, 0.f) + 1e-5f);
    u16* yr = Y + (long long)row * 384;
#pragma unroll
    for (int i = 0; i < 6; ++i) {
        int c = i * 64 + lane;
        yr[c] = f2b((v[i] - mean) * rs * g[c] + b[c]);
    }
}

// ---------------------------------------------------------------------------
// m97-style 128x128 tile K-loop: linear LDS [128][32], global_load_lds w16.
#define MFMA_TILE_LOOP128(Aptr, Bptr, LDA, LDB, K0, K1)                        \
    for (int k0 = (K0); k0 < (K1); k0 += 32) {                                 \
        __syncthreads();                                                       \
        {                                                                      \
            int rlo = lane >> 2;                                               \
            int c8 = (lane & 3) * 8;                                           \
            gl2lds16(&As[(wv * 32) * 32],                                      \
                (Aptr) + (long long)(m0 + wv * 32 + rlo) * (LDA) + k0 + c8);   \
            gl2lds16(&As[(wv * 32 + 16) * 32],                                 \
                (Aptr) + (long long)(m0 + wv * 32 + 16 + rlo) * (LDA) + k0 + c8); \
            gl2lds16(&Bs[(wv * 32) * 32],                                      \
                (Bptr) + (long long)(n0 + wv * 32 + rlo) * (LDB) + k0 + c8);   \
            gl2lds16(&Bs[(wv * 32 + 16) * 32],                                 \
                (Bptr) + (long long)(n0 + wv * 32 + 16 + rlo) * (LDB) + k0 + c8); \
        }                                                                      \
        __syncthreads();                                                       \
        bf16x8 a0 = *(const bf16x8*)&As[(wv * 32 + lr) * 32 + lq * 8];         \
        bf16x8 a1 = *(const bf16x8*)&As[(wv * 32 + 16 + lr) * 32 + lq * 8];    \
        _Pragma("unroll")                                                      \
        for (int ns = 0; ns < 8; ++ns) {                                       \
            bf16x8 b = *(const bf16x8*)&Bs[(ns * 16 + lr) * 32 + lq * 8];      \
            acc[0][ns] = __builtin_amdgcn_mfma_f32_16x16x32_bf16(a0, b, acc[0][ns], 0, 0, 0); \
            acc[1][ns] = __builtin_amdgcn_mfma_f32_16x16x32_bf16(a1, b, acc[1][ns], 0, 0, 0); \
        }                                                                      \
    }

// Generic GEMM with z-strides: C = act(scale*A@WT^T + bias) + res.
template<int RES_F32, int OUT_F32>
__global__ __launch_bounds__(256) void gemm_mfma(
    const u16* __restrict__ A, const u16* __restrict__ WT,
    const float* __restrict__ bias, const void* __restrict__ res,
    void* __restrict__ C,
    int M, int N, int K, int lda, int ldb, int ldc, int ldres,
    float scale, int relu, int resmask,
    long long zsA, long long zsB, long long zsC)
{
    __shared__ u16 As[128 * 32];
    __shared__ u16 Bs[128 * 32];
    const int tid = threadIdx.x;
    const int wv = tid >> 6, lane = tid & 63;
    const int lr = lane & 15, lq = lane >> 4;
    int bx = blockIdx.x, by = blockIdx.y, bz = blockIdx.z;
    xcd_remap(bx, by, bz);
    const int m0 = bx * 128;
    const int n0 = by * 128;
    const u16* Az = A + bz * zsA;
    const u16* Bz = WT + bz * zsB;
    const long long czoff = bz * zsC;

    floatx4 acc[2][8];
#pragma unroll
    for (int i = 0; i < 2; ++i)
#pragma unroll
        for (int j = 0; j < 8; ++j)
            acc[i][j] = (floatx4){0.f, 0.f, 0.f, 0.f};

    MFMA_TILE_LOOP128(Az, Bz, lda, ldb, 0, K)

    float bi[8];
#pragma unroll
    for (int ns = 0; ns < 8; ++ns)
        bi[ns] = bias ? bias[n0 + ns * 16 + lr] : 0.f;

#pragma unroll
    for (int ms = 0; ms < 2; ++ms) {
#pragma unroll
        for (int r = 0; r < 4; ++r) {
            int m = m0 + wv * 32 + ms * 16 + lq * 4 + r;
#pragma unroll
            for (int ns = 0; ns < 8; ++ns) {
                int col = n0 + ns * 16 + lr;
                float v = acc[ms][ns][r] * scale + bi[ns];
                if (relu) v = fmaxf(v, 0.f);
                if (res) {
                    long long ro = (long long)(m & resmask) * ldres + col;
                    v += RES_F32 ? ((const float*)res)[ro]
                                 : b2f(((const u16*)res)[ro]);
                }
                long long co = czoff + (long long)m * ldc + col;
                if (OUT_F32) ((float*)C)[co] = v;
                else         ((u16*)C)[co] = f2b(v);
            }
        }
    }
}

// ---------------------------------------------------------------------------
// S-with-exp GEMM (z over group): P = exp(clamp(scale*q@K^T)), den += row sums.
// Epilogue transposes P through LDS so global stores are full 16B lines.
__global__ __launch_bounds__(256) void gemm_exp(
    const u16* __restrict__ A, const u16* __restrict__ WT,
    u16* __restrict__ P, float* __restrict__ den,
    int K, int lda, int ldb, int ldc, float scale,
    long long zsB, long long zsP)
{
    __shared__ u16 sh[8192];          // As(8KB) + Bs(8KB); reused as P scratch
    u16* As = sh;
    u16* Bs = sh + 4096;
    const int tid = threadIdx.x;
    const int wv = tid >> 6, lane = tid & 63;
    const int lr = lane & 15, lq = lane >> 4;
    int bx = blockIdx.x, by = blockIdx.y, bz = blockIdx.z;
    xcd_remap(bx, by, bz);
    const int m0 = bx * 128;
    const int n0 = by * 128;
    const u16* Bz = WT + bz * zsB;
    u16* Pz = P + bz * zsP;
    float* dz = den + bz * 512;

    floatx4 acc[2][8];
#pragma unroll
    for (int i = 0; i < 2; ++i)
#pragma unroll
        for (int j = 0; j < 8; ++j)
            acc[i][j] = (floatx4){0.f, 0.f, 0.f, 0.f};

    MFMA_TILE_LOOP128(A, Bz, lda, ldb, 0, K)

    float srow[2][4] = {};
#pragma unroll
    for (int ms = 0; ms < 2; ++ms) {
        __syncthreads();                    // previous pass / k-loop LDS done
#pragma unroll
        for (int ns = 0; ns < 8; ++ns)
#pragma unroll
            for (int r = 0; r < 4; ++r) {
                float l = acc[ms][ns][r] * scale;
                l = fminf(fmaxf(l, -60.f), 60.f);
                float p = __expf(l);
                srow[ms][r] += p;
                sh[(wv * 16 + lq * 4 + r) * 128 + ns * 16 + lr] = f2b(p);
            }
        __syncthreads();
        // stream out 64 rows x 256B as uint4 (16 consecutive lanes = 256B row)
#pragma unroll
        for (int j = 0; j < 4; ++j) {
            int idx = j * 256 + tid;
            int rl = idx >> 4, ch = idx & 15;
            int m = m0 + ((rl >> 4) << 5) + ms * 16 + (rl & 15);
            *(uint4*)&Pz[(long long)m * ldc + n0 + ch * 8] =
                *(const uint4*)&sh[rl * 128 + ch * 8];
        }
    }
#pragma unroll
    for (int ms = 0; ms < 2; ++ms)
#pragma unroll
        for (int r = 0; r < 4; ++r) {
            float s = srow[ms][r];
            s += __shfl_xor(s, 1, 64);
            s += __shfl_xor(s, 2, 64);
            s += __shfl_xor(s, 4, 64);
            s += __shfl_xor(s, 8, 64);
            if (lr == 0)
                atomicAdd(&dz[m0 + wv * 32 + ms * 16 + lq * 4 + r], s);
        }
}

// ---------------------------------------------------------------------------
// Split-K PV over group: z = g*SPLIT + s; part[z] = P_g[:, ks..] @ VT_g[:, ks..]^T
__global__ __launch_bounds__(256) void gemm_pv(
    const u16* __restrict__ P, const u16* __restrict__ VT,
    float* __restrict__ part, int SPLIT)
{
    __shared__ u16 As[128 * 32];
    __shared__ u16 Bs[128 * 32];
    const int tid = threadIdx.x;
    const int wv = tid >> 6, lane = tid & 63;
    const int lr = lane & 15, lq = lane >> 4;
    int bx = blockIdx.x, by = blockIdx.y, bz = blockIdx.z;
    xcd_remap(bx, by, bz);
    const int m0 = bx * 128;
    const int n0 = by * 128;
    const int g = bz / SPLIT, sp = bz - g * SPLIT;
    const int chunk = 8192 / SPLIT;
    const u16* Az = P + (long long)g * 512 * 8192;
    const u16* Bz = VT + (long long)g * 384 * 8192;

    floatx4 acc[2][8];
#pragma unroll
    for (int i = 0; i < 2; ++i)
#pragma unroll
        for (int j = 0; j < 8; ++j)
            acc[i][j] = (floatx4){0.f, 0.f, 0.f, 0.f};

    MFMA_TILE_LOOP128(Az, Bz, 8192, 8192, sp * chunk, (sp + 1) * chunk)

    float* pz = part + (long long)bz * 512 * 384;
#pragma unroll
    for (int ms = 0; ms < 2; ++ms)
#pragma unroll
        for (int r = 0; r < 4; ++r) {
            int m = m0 + wv * 32 + ms * 16 + lq * 4 + r;
#pragma unroll
            for (int ns = 0; ns < 8; ++ns) {
                int col = n0 + ns * 16 + lr;
                pz[(long long)m * 384 + col] = acc[ms][ns][r];
            }
        }
}

// ---------------------------------------------------------------------------
// PV reduce over group: ao[g][q][d] = (sum_s part[g*SPLIT+s][q][d]) / den[g*512+q]
__global__ __launch_bounds__(256) void pv_reduce_kernel(
    const float* __restrict__ part, const float* __restrict__ den,
    u16* __restrict__ AO, int SPLIT)
{
    int idx = blockIdx.x * 256 + threadIdx.x;   // G*512*96 threads
    int q = idx / 96, j = (idx - q * 96) * 4;   // q in [0, G*512)
    int g = q >> 9, ql = q & 511;
    float4 s = make_float4(0.f, 0.f, 0.f, 0.f);
    for (int sp = 0; sp < SPLIT; ++sp) {
        const float* pz = part + (((long long)(g * SPLIT + sp) * 512 + ql) * 384 + j);
        float4 v = *(const float4*)pz;
        s.x += v.x; s.y += v.y; s.z += v.z; s.w += v.w;
    }
    float inv = 1.0f / den[q];
    s.x *= inv; s.y *= inv; s.z *= inv; s.w *= inv;
    stb4(AO + (long long)q * 384 + j, s);
}

// ---------------------------------------------------------------------------
// FF1 + GEGLU fused: gl = a * gelu(g). 128x(64+64) tile, async staging.
__global__ __launch_bounds__(256) void gemm_ff1_geglu(
    const u16* __restrict__ A, const u16* __restrict__ WT,
    const float* __restrict__ bias, u16* __restrict__ C,
    int K, int lda, int ldb, int ldc)
{
    __shared__ u16 As[128 * 32];
    __shared__ u16 Bs[128 * 32];
    const int tid = threadIdx.x;
    const int wv = tid >> 6, lane = tid & 63;
    const int lr = lane & 15, lq = lane >> 4;
    int bx = blockIdx.x, by = blockIdx.y, bz = blockIdx.z;
    xcd_remap(bx, by, bz);
    const int m0 = bx * 128;
    const int n0 = by * 64;

    floatx4 accA[2][4], accG[2][4];
#pragma unroll
    for (int i = 0; i < 2; ++i)
#pragma unroll
        for (int j = 0; j < 4; ++j) {
            accA[i][j] = (floatx4){0.f, 0.f, 0.f, 0.f};
            accG[i][j] = (floatx4){0.f, 0.f, 0.f, 0.f};
        }

    for (int k0 = 0; k0 < K; k0 += 32) {
        __syncthreads();
        {
            int rlo = lane >> 2;
            int c8 = (lane & 3) * 8;
            gl2lds16(&As[(wv * 32) * 32],
                A + (long long)(m0 + wv * 32 + rlo) * lda + k0 + c8);
            gl2lds16(&As[(wv * 32 + 16) * 32],
                A + (long long)(m0 + wv * 32 + 16 + rlo) * lda + k0 + c8);
            int r0 = wv * 32 + rlo;
            int r1 = r0 + 16;
            int wrow0 = (r0 < 64) ? (n0 + r0) : (1536 + n0 + r0 - 64);
            int wrow1 = (r1 < 64) ? (n0 + r1) : (1536 + n0 + r1 - 64);
            gl2lds16(&Bs[(wv * 32) * 32],
                WT + (long long)wrow0 * ldb + k0 + c8);
            gl2lds16(&Bs[(wv * 32 + 16) * 32],
                WT + (long long)wrow1 * ldb + k0 + c8);
        }
        __syncthreads();
        bf16x8 a0 = *(const bf16x8*)&As[(wv * 32 + lr) * 32 + lq * 8];
        bf16x8 a1 = *(const bf16x8*)&As[(wv * 32 + 16 + lr) * 32 + lq * 8];
#pragma unroll
        for (int ns = 0; ns < 4; ++ns) {
            bf16x8 bA = *(const bf16x8*)&Bs[(ns * 16 + lr) * 32 + lq * 8];
            bf16x8 bG = *(const bf16x8*)&Bs[((64 + ns * 16) + lr) * 32 + lq * 8];
            accA[0][ns] = __builtin_amdgcn_mfma_f32_16x16x32_bf16(a0, bA, accA[0][ns], 0, 0, 0);
            accA[1][ns] = __builtin_amdgcn_mfma_f32_16x16x32_bf16(a1, bA, accA[1][ns], 0, 0, 0);
            accG[0][ns] = __builtin_amdgcn_mfma_f32_16x16x32_bf16(a0, bG, accG[0][ns], 0, 0, 0);
            accG[1][ns] = __builtin_amdgcn_mfma_f32_16x16x32_bf16(a1, bG, accG[1][ns], 0, 0, 0);
        }
    }

    float ba[4], bg[4];
#pragma unroll
    for (int ns = 0; ns < 4; ++ns) {
        ba[ns] = bias[n0 + ns * 16 + lr];
        bg[ns] = bias[1536 + n0 + ns * 16 + lr];
    }
#pragma unroll
    for (int ms = 0; ms < 2; ++ms)
#pragma unroll
        for (int r = 0; r < 4; ++r) {
            int m = m0 + wv * 32 + ms * 16 + lq * 4 + r;
#pragma unroll
            for (int ns = 0; ns < 4; ++ns) {
                int col = n0 + ns * 16 + lr;
                float a = accA[ms][ns][r] + ba[ns];
                float g = accG[ms][ns][r] + bg[ns];
                float v = a * 0.5f * g * (1.0f + erff(g * 0.70710678118654752f));
                C[(long long)m * ldc + col] = f2b(v);
            }
        }
}

// ---------------------------------------------------------------------------
extern "C" void kernel_launch(void* const* d_in, const int* in_sizes, int n_in,
                              void* d_out, int out_size, void* d_ws, size_t ws_size,
                              hipStream_t stream) {
    const float* x     = (const float*)d_in[0];
    const float* w0    = (const float*)d_in[1];
    const float* b0    = (const float*)d_in[2];
    const float* w1    = (const float*)d_in[3];
    const float* b1    = (const float*)d_in[4];
    const float* w2    = (const float*)d_in[5];
    const float* b2    = (const float*)d_in[6];
    const float* w3    = (const float*)d_in[7];
    const float* b3    = (const float*)d_in[8];
    const float* query = (const float*)d_in[9];
    const float* lnqg  = (const float*)d_in[10];
    const float* lnqb  = (const float*)d_in[11];
    const float* lncg  = (const float*)d_in[12];
    const float* lncb  = (const float*)d_in[13];
    const float* wq    = (const float*)d_in[14];
    const float* wkv   = (const float*)d_in[15];
    const float* wo    = (const float*)d_in[16];
    const float* bo    = (const float*)d_in[17];
    const float* lnfg  = (const float*)d_in[18];
    const float* lnfb  = (const float*)d_in[19];
    const float* ffw1  = (const float*)d_in[20];
    const float* ffb1  = (const float*)d_in[21];
    const float* ffw2  = (const float*)d_in[22];
    const float* ffb2  = (const float*)d_in[23];
    float* out = (float*)d_out;
    char* wsb = (char*)d_ws;

    // ---- group size selection from ws_size ----
    auto need = [](int G) -> size_t {
        return (size_t)G * (3LL * 6291456 + 8388608)    // bufA,bufB,VT,P
             + 25165824                                 // part (32 slots)
             + 6291456                                  // ao_all
             + 2 * 393216 + 32768                       // qn, qb, den
             + 5603328;                                 // weight pool
    };
    int G = 2;
    if      (ws_size >= need(16)) G = 16;
    else if (ws_size >= need(8))  G = 8;
    else if (ws_size >= need(4))  G = 4;
    const int SPLIT = 32 / G;

    long long off = 0;
    u16*   bufA   = (u16*)(wsb + off); off += (long long)G * 6291456;
    u16*   bufB   = (u16*)(wsb + off); off += (long long)G * 6291456;
    u16*   VTb    = (u16*)(wsb + off); off += (long long)G * 6291456;
    u16*   Pb     = (u16*)(wsb + off); off += (long long)G * 8388608;
    float* part   = (float*)(wsb + off); off += 25165824;
    u16*   ao_all = (u16*)(wsb + off); off += 6291456;
    u16*   qn     = (u16*)(wsb + off); off += 393216;
    u16*   qb     = (u16*)(wsb + off); off += 393216;
    float* den    = (float*)(wsb + off); off += 32768;
    u16*   w1T    = (u16*)(wsb + off); off += 294912;
    u16*   w2T    = (u16*)(wsb + off); off += 294912;
    u16*   w3T    = (u16*)(wsb + off); off += 294912;
    u16*   wqT    = (u16*)(wsb + off); off += 294912;
    u16*   wkvT   = (u16*)(wsb + off); off += 589824;   // +147456 elems = wvT
    u16*   woT    = (u16*)(wsb + off); off += 294912;
    u16*   ffw1T  = (u16*)(wsb + off); off += 2359296;
    u16*   ffw2T  = (u16*)(wsb + off); off += 1179648;
    // phase-2 overlays (bufA/bufB/VT region is dead by then; >= 37.75MB for G>=2)
    u16*   x1_all = (u16*)(wsb + 0);
    u16*   f0_all = (u16*)(wsb + 6291456);
    u16*   gl_all = (u16*)(wsb + 12582912);   // 25.2MB, ends at 37748736

    const int FULLMASK = 0x3FFFFFFF;

    // ---- setup ----
    wconv_kernel<<<576,  256, 0, stream>>>(w1,   w1T,   384, 384);
    wconv_kernel<<<576,  256, 0, stream>>>(w2,   w2T,   384, 384);
    wconv_kernel<<<576,  256, 0, stream>>>(w3,   w3T,   384, 384);
    wconv_kernel<<<576,  256, 0, stream>>>(wq,   wqT,   384, 384);
    wconv_kernel<<<1152, 256, 0, stream>>>(wkv,  wkvT,  384, 768);
    wconv_kernel<<<576,  256, 0, stream>>>(wo,   woT,   384, 384);
    wconv_kernel<<<4608, 256, 0, stream>>>(ffw1, ffw1T, 384, 3072);
    wconv_kernel<<<2304, 256, 0, stream>>>(ffw2, ffw2T, 1536, 384);
    hipMemsetAsync(den, 0, 16 * 512 * sizeof(float), stream);
    ln_kernel<1><<<128, 256, 0, stream>>>(query, lnqg, lnqb, qn, 512);
    gemm_mfma<0, 0><<<dim3(4, 3), 256, 0, stream>>>(qn, wqT, nullptr, nullptr, qb,
        512, 384, 384, 384, 384, 384, 0, 1.f, 0, FULLMASK, 0, 0, 0);

    // ---- phase 1: groups of G batches ----
    const int MG = G * 8192;
    for (int base = 0; base < 16; base += G) {
        const float* xg = x + (long long)base * 24576;

        layer0_kernel<<<G * 3072, 256, 0, stream>>>(xg, w0, b0, bufA, G * 786432);
        gemm_mfma<0, 0><<<dim3(MG / 128, 3), 256, 0, stream>>>(bufA, w1T, b1, nullptr, bufB,
            MG, 384, 384, 384, 384, 384, 0, 1.f, 1, FULLMASK, 0, 0, 0);
        gemm_mfma<0, 0><<<dim3(MG / 128, 3), 256, 0, stream>>>(bufB, w2T, b2, nullptr, bufA,
            MG, 384, 384, 384, 384, 384, 0, 1.f, 1, FULLMASK, 0, 0, 0);
        gemm_mfma<0, 0><<<dim3(MG / 128, 3), 256, 0, stream>>>(bufA, w3T, b3, nullptr, bufB,
            MG, 384, 384, 384, 384, 384, 0, 1.f, 0, FULLMASK, 0, 0, 0);   // ctx -> bufB
        ln_kernel<0><<<MG / 4, 256, 0, stream>>>(bufB, lncg, lncb, bufA, MG);  // kn -> bufA
        // K_all = kn @ wk -> bufB
        gemm_mfma<0, 0><<<dim3(MG / 128, 3), 256, 0, stream>>>(bufA, wkvT, nullptr, nullptr, bufB,
            MG, 384, 384, 384, 384, 384, 0, 1.f, 0, FULLMASK, 0, 0, 0);
        // VT_g = wv^T @ kn_g^T  (z over group)
        gemm_mfma<0, 0><<<dim3(3, 64, G), 256, 0, stream>>>(wkvT + 147456, bufA,
            nullptr, nullptr, VTb, 384, 8192, 384, 384, 384, 8192, 0, 1.f, 0, FULLMASK,
            0, 8192LL * 384, 384LL * 8192);
        // P_g = exp(scale * q @ K_g^T), den += row sums
        gemm_exp<<<dim3(4, 64, G), 256, 0, stream>>>(qb, bufB, Pb, den + base * 512,
            384, 384, 384, 8192, 0.05103103630798288f, 8192LL * 384, 512LL * 8192);
        // PV split-K partials (z = g*SPLIT + s, 32 total)
        gemm_pv<<<dim3(4, 3, 32), 256, 0, stream>>>(Pb, VTb, part, SPLIT);
        // reduce -> ao_all[base..base+G)
        pv_reduce_kernel<<<G * 192, 256, 0, stream>>>(part, den + base * 512,
            ao_all + (long long)base * 196608, SPLIT);
    }

    // ---- phase 2: batched across all 16 ----
    gemm_mfma<1, 0><<<dim3(64, 3), 256, 0, stream>>>(ao_all, woT, bo, query, x1_all,
        8192, 384, 384, 384, 384, 384, 384, 1.f, 0, 511, 0, 0, 0);
    ln_kernel<0><<<2048, 256, 0, stream>>>(x1_all, lnfg, lnfb, f0_all, 8192);
    gemm_ff1_geglu<<<dim3(64, 24), 256, 0, stream>>>(f0_all, ffw1T, ffb1, gl_all,
        384, 384, 384, 1536);
    gemm_mfma<0, 1><<<dim3(64, 3), 256, 0, stream>>>(gl_all, ffw2T, ffb2, x1_all, out,
        8192, 384, 1536, 1536, 1536, 384, 384, 1.f, 0, FULLMASK, 0, 0, 0);
}